// Round 1
// baseline (2113.570 us; speedup 1.0000x reference)
//
#include <hip/hip_runtime.h>
#include <hip/hip_bf16.h>

// Problem: N=500000, D=128, K=2048
//  y = x @ p / ||p||            [N]
//  top_vals, top_idx = top_k(y, K)   (desc, ties -> lower index first)
//  out = x[top_idx] * tanh(top_vals)[:,None]   [K, D] fp32

#define HIST_BITS 12
#define HIST_BINS (1 << HIST_BITS)   // 4096
#define SORTN 8192                    // candidate capacity (k + boundary-bin, ~2900 expected)

__device__ __forceinline__ unsigned mono_key(float f) {
    unsigned u = __float_as_uint(f);
    return (u & 0x80000000u) ? ~u : (u | 0x80000000u);
}
__device__ __forceinline__ float mono_key_inv(unsigned mk) {
    unsigned u = (mk & 0x80000000u) ? (mk ^ 0x80000000u) : ~mk;
    return __uint_as_float(u);
}

// ---------------- kernel 1: scores + histogram ----------------
// one row per wave64; lane i loads x[row][2i..2i+1] (float2) -> 512B coalesced/wave
__global__ void score_kernel(const float* __restrict__ x, const float* __restrict__ p,
                             float* __restrict__ y, unsigned* __restrict__ hist, int N) {
    int wib  = threadIdx.x >> 6;
    int lane = threadIdx.x & 63;
    long long row = (long long)blockIdx.x * (blockDim.x >> 6) + wib;
    if (row >= N) return;
    float2 xv = ((const float2*)(x + row * 128))[lane];
    float2 pv = ((const float2*)p)[lane];
    double dot = (double)xv.x * (double)pv.x + (double)xv.y * (double)pv.y;
    double pp  = (double)pv.x * (double)pv.x + (double)pv.y * (double)pv.y;
    #pragma unroll
    for (int off = 32; off > 0; off >>= 1) {
        dot += __shfl_down(dot, off, 64);
        pp  += __shfl_down(pp,  off, 64);
    }
    if (lane == 0) {
        float yf = (float)(dot / sqrt(pp));
        y[row] = yf;
        atomicAdd(&hist[mono_key(yf) >> (32 - HIST_BITS)], 1u);
    }
}

// ---------------- kernel 2: find threshold bin ----------------
// suffix-scan hist; B = largest bin with (count of elements in bins >= B) >= k
__global__ void threshold_kernel(const unsigned* __restrict__ hist,
                                 const int* __restrict__ kptr, int* __restrict__ res) {
    __shared__ unsigned s[HIST_BINS];
    int t = threadIdx.x;               // 1024 threads
    for (int i = t; i < HIST_BINS; i += 1024) s[i] = hist[i];
    __syncthreads();
    for (int off = 1; off < HIST_BINS; off <<= 1) {
        unsigned v[HIST_BINS / 1024];
        #pragma unroll
        for (int j = 0; j < HIST_BINS / 1024; j++) {
            int i = t + j * 1024;
            v[j] = s[i] + ((i + off < HIST_BINS) ? s[i + off] : 0u);
        }
        __syncthreads();
        #pragma unroll
        for (int j = 0; j < HIST_BINS / 1024; j++) s[t + j * 1024] = v[j];
        __syncthreads();
    }
    int k = *kptr;
    #pragma unroll
    for (int j = 0; j < HIST_BINS / 1024; j++) {
        int i = t + j * 1024;
        int c     = (int)s[i];
        int cnext = (i + 1 < HIST_BINS) ? (int)s[i + 1] : 0;
        if (c >= k && cnext < k) { res[0] = i; res[1] = cnext; }
    }
}

// ---------------- kernel 3: compact candidates ----------------
// key64 = mkey<<32 | ~idx  -> sort desc == value desc, ties idx asc (jax tie-break)
__global__ void compact_kernel(const float* __restrict__ y, const int* __restrict__ res,
                               unsigned long long* __restrict__ pairs, int* __restrict__ cnt,
                               int N) {
    int B = res[0];
    int stride = gridDim.x * blockDim.x;
    for (int i = blockIdx.x * blockDim.x + threadIdx.x; i < N; i += stride) {
        unsigned mk = mono_key(y[i]);
        if ((int)(mk >> (32 - HIST_BITS)) >= B) {
            int pos = atomicAdd(cnt, 1);
            if (pos < SORTN)
                pairs[pos] = ((unsigned long long)mk << 32) | (unsigned)~(unsigned)i;
        }
    }
}

// ---------------- kernel 4: bitonic sort (desc) in LDS ----------------
__global__ void sort_kernel(unsigned long long* __restrict__ pairs, const int* __restrict__ cnt) {
    __shared__ unsigned long long s[SORTN];
    int n = *cnt; if (n > SORTN) n = SORTN;
    int t = threadIdx.x;               // 1024 threads
    for (int i = t; i < SORTN; i += 1024) s[i] = (i < n) ? pairs[i] : 0ull;
    __syncthreads();
    for (int k2 = 2; k2 <= SORTN; k2 <<= 1) {
        for (int j = k2 >> 1; j > 0; j >>= 1) {
            for (int i = t; i < SORTN; i += 1024) {
                int ixj = i ^ j;
                if (ixj > i) {
                    unsigned long long a = s[i], b = s[ixj];
                    bool up = ((i & k2) == 0);           // descending overall
                    if (up ? (a < b) : (a > b)) { s[i] = b; s[ixj] = a; }
                }
            }
            __syncthreads();
        }
    }
    for (int i = t; i < SORTN; i += 1024) pairs[i] = s[i];
}

// ---------------- kernel 5: gather + tanh scale ----------------
__global__ void gather_kernel(const float* __restrict__ x,
                              const unsigned long long* __restrict__ pairs,
                              float* __restrict__ out) {
    int j = blockIdx.x;                // 0..K-1
    unsigned long long key = pairs[j];
    unsigned mk  = (unsigned)(key >> 32);
    unsigned idx = ~(unsigned)(key & 0xFFFFFFFFull);
    float scale = tanhf(mono_key_inv(mk));
    int t = threadIdx.x;               // 128 threads
    out[(size_t)j * 128 + t] = x[(size_t)idx * 128 + t] * scale;
}

extern "C" void kernel_launch(void* const* d_in, const int* in_sizes, int n_in,
                              void* d_out, int out_size, void* d_ws, size_t ws_size,
                              hipStream_t stream) {
    const float* x = (const float*)d_in[0];
    const float* p = (const float*)d_in[1];
    const int*   kptr = (const int*)d_in[2];
    float* out = (float*)d_out;

    const int D = in_sizes[1];                 // 128
    const int N = in_sizes[0] / D;             // 500000
    const int K = out_size / D;                // 2048
    (void)n_in; (void)ws_size;

    // workspace layout
    unsigned char* w = (unsigned char*)d_ws;
    float* y = (float*)w;                                       // N floats
    size_t off = ((size_t)N * sizeof(float) + 255) & ~(size_t)255;
    unsigned* hist = (unsigned*)(w + off);                      // HIST_BINS u32
    int* cnt = (int*)(w + off + HIST_BINS * sizeof(unsigned));  // 1 int
    int* res = cnt + 1;                                         // 2 ints
    size_t off2 = (off + HIST_BINS * sizeof(unsigned) + 3 * sizeof(int) + 255) & ~(size_t)255;
    unsigned long long* pairs = (unsigned long long*)(w + off2); // SORTN u64

    // zero hist + cnt (ws is poisoned 0xAA before every call)
    hipMemsetAsync(hist, 0, HIST_BINS * sizeof(unsigned) + sizeof(int), stream);

    {   // scores: 4 rows per 256-thread block (1 row/wave)
        int rows_per_block = 256 / 64;
        int grid = (N + rows_per_block - 1) / rows_per_block;
        score_kernel<<<grid, 256, 0, stream>>>(x, p, y, hist, N);
    }
    threshold_kernel<<<1, 1024, 0, stream>>>(hist, kptr, res);
    compact_kernel<<<1024, 256, 0, stream>>>(y, res, pairs, cnt, N);
    sort_kernel<<<1, 1024, 0, stream>>>(pairs, cnt);
    gather_kernel<<<K, 128, 0, stream>>>(x, pairs, out);
}

// Round 2
// 505.892 us; speedup vs baseline: 4.1779x; 4.1779x over previous
//
#include <hip/hip_runtime.h>
#include <hip/hip_bf16.h>

// Problem: N=500000, D=128, K=2048
//  y = x @ p / ||p||; top_k(y, K) desc (ties -> lower index); out = x[idx] * tanh(vals)[:,None]

#define HIST_BITS 12
#define HIST_BINS (1 << HIST_BITS)   // 4096
#define HIST_SHIFT (32 - HIST_BITS)  // 20
#define SORTN 8192                   // candidate capacity (k + boundary bin, ~2800 expected)

__device__ __forceinline__ unsigned mono_key(float f) {
    unsigned u = __float_as_uint(f);
    return (u & 0x80000000u) ? ~u : (u | 0x80000000u);
}
__device__ __forceinline__ float mono_key_inv(unsigned mk) {
    unsigned u = (mk & 0x80000000u) ? (mk ^ 0x80000000u) : ~mk;
    return __uint_as_float(u);
}

// ---------------- kernel 1: scores only (NO atomics) ----------------
// 32 lanes per row, float4 loads: 2 rows per wave-iteration, 5 xor-shuffle rounds.
// Each wave owns a contiguous chunk of rpw rows (rpw even).
__global__ void score_kernel(const float* __restrict__ x, const float* __restrict__ p,
                             float* __restrict__ y, int N, int rpw) {
    int lane = threadIdx.x & 63;
    int half = lane >> 5;            // 0: even row of pair, 1: odd row
    int l32  = lane & 31;
    long long gwave = ((long long)blockIdx.x * blockDim.x + threadIdx.x) >> 6;
    long long start = gwave * rpw;
    if (start >= N) return;

    float4 pq = ((const float4*)p)[l32];
    double pp = (double)pq.x * pq.x + (double)pq.y * pq.y +
                (double)pq.z * pq.z + (double)pq.w * pq.w;
    #pragma unroll
    for (int off = 16; off > 0; off >>= 1) pp += __shfl_xor(pp, off, 64);
    double rinv = 1.0 / sqrt(pp);    // same value in both halves

    long long rend = start + rpw; if (rend > N) rend = N;
    for (long long r0 = start; r0 < rend; r0 += 2) {
        long long row = r0 + half;
        bool valid = row < N;
        float4 xq = valid ? ((const float4*)(x + row * 128))[l32]
                          : make_float4(0.f, 0.f, 0.f, 0.f);
        double d = (double)xq.x * pq.x + (double)xq.y * pq.y +
                   (double)xq.z * pq.z + (double)xq.w * pq.w;
        #pragma unroll
        for (int off = 16; off > 0; off >>= 1) d += __shfl_xor(d, off, 64);
        if (l32 == 0 && valid) y[row] = (float)(d * rinv);
    }
}

// ---------------- kernel 2: histogram over y (LDS-aggregated) ----------------
__global__ void hist_kernel(const float* __restrict__ y, unsigned* __restrict__ hist, int N) {
    __shared__ unsigned h[HIST_BINS];
    for (int i = threadIdx.x; i < HIST_BINS; i += blockDim.x) h[i] = 0;
    __syncthreads();
    int stride = gridDim.x * blockDim.x;
    for (int i = blockIdx.x * blockDim.x + threadIdx.x; i < N; i += stride)
        atomicAdd(&h[mono_key(y[i]) >> HIST_SHIFT], 1u);
    __syncthreads();
    for (int i = threadIdx.x; i < HIST_BINS; i += blockDim.x) {
        unsigned v = h[i];
        if (v) atomicAdd(&hist[i], v);
    }
}

// ---------------- kernel 3: find threshold bin ----------------
__global__ void threshold_kernel(const unsigned* __restrict__ hist,
                                 const int* __restrict__ kptr, int* __restrict__ res) {
    __shared__ unsigned s[HIST_BINS];
    int t = threadIdx.x;             // 1024 threads
    for (int i = t; i < HIST_BINS; i += 1024) s[i] = hist[i];
    __syncthreads();
    for (int off = 1; off < HIST_BINS; off <<= 1) {
        unsigned v[HIST_BINS / 1024];
        #pragma unroll
        for (int j = 0; j < HIST_BINS / 1024; j++) {
            int i = t + j * 1024;
            v[j] = s[i] + ((i + off < HIST_BINS) ? s[i + off] : 0u);
        }
        __syncthreads();
        #pragma unroll
        for (int j = 0; j < HIST_BINS / 1024; j++) s[t + j * 1024] = v[j];
        __syncthreads();
    }
    int k = *kptr;
    #pragma unroll
    for (int j = 0; j < HIST_BINS / 1024; j++) {
        int i = t + j * 1024;
        int c     = (int)s[i];
        int cnext = (i + 1 < HIST_BINS) ? (int)s[i + 1] : 0;
        if (c >= k && cnext < k) { res[0] = i; res[1] = cnext; }
    }
}

// ---------------- kernel 4: compact candidates (block-aggregated atomic) ----------------
// key64 = mkey<<32 | ~idx  -> desc sort == value desc, ties idx asc (jax tie-break)
__global__ void compact_kernel(const float* __restrict__ y, const int* __restrict__ res,
                               unsigned long long* __restrict__ pairs, int* __restrict__ cnt,
                               int N) {
    __shared__ int lcnt, lbase;
    if (threadIdx.x == 0) lcnt = 0;
    __syncthreads();
    int B = res[0];
    int i = blockIdx.x * blockDim.x + threadIdx.x;
    int lpos = -1;
    unsigned mk = 0;
    if (i < N) {
        mk = mono_key(y[i]);
        if ((int)(mk >> HIST_SHIFT) >= B) lpos = atomicAdd(&lcnt, 1);
    }
    __syncthreads();
    if (threadIdx.x == 0 && lcnt > 0) lbase = atomicAdd(cnt, lcnt);
    __syncthreads();
    if (lpos >= 0) {
        int pos = lbase + lpos;
        if (pos < SORTN)
            pairs[pos] = ((unsigned long long)mk << 32) | (unsigned)~(unsigned)i;
    }
}

// ---------------- kernel 5: bitonic sort (desc) in LDS ----------------
__global__ void sort_kernel(unsigned long long* __restrict__ pairs, const int* __restrict__ cnt) {
    __shared__ unsigned long long s[SORTN];
    int n = *cnt; if (n > SORTN) n = SORTN;
    int t = threadIdx.x;             // 1024 threads
    for (int i = t; i < SORTN; i += 1024) s[i] = (i < n) ? pairs[i] : 0ull;
    __syncthreads();
    for (int k2 = 2; k2 <= SORTN; k2 <<= 1) {
        for (int j = k2 >> 1; j > 0; j >>= 1) {
            for (int i = t; i < SORTN; i += 1024) {
                int ixj = i ^ j;
                if (ixj > i) {
                    unsigned long long a = s[i], b = s[ixj];
                    bool up = ((i & k2) == 0);      // descending overall
                    if (up ? (a < b) : (a > b)) { s[i] = b; s[ixj] = a; }
                }
            }
            __syncthreads();
        }
    }
    for (int i = t; i < SORTN; i += 1024) pairs[i] = s[i];
}

// ---------------- kernel 6: gather + tanh scale ----------------
__global__ void gather_kernel(const float* __restrict__ x,
                              const unsigned long long* __restrict__ pairs,
                              float* __restrict__ out) {
    int j = blockIdx.x;              // 0..K-1
    unsigned long long key = pairs[j];
    unsigned mk  = (unsigned)(key >> 32);
    unsigned idx = ~(unsigned)(key & 0xFFFFFFFFull);
    float scale = tanhf(mono_key_inv(mk));
    int t = threadIdx.x;             // 128 threads
    out[(size_t)j * 128 + t] = x[(size_t)idx * 128 + t] * scale;
}

extern "C" void kernel_launch(void* const* d_in, const int* in_sizes, int n_in,
                              void* d_out, int out_size, void* d_ws, size_t ws_size,
                              hipStream_t stream) {
    const float* x = (const float*)d_in[0];
    const float* p = (const float*)d_in[1];
    const int*   kptr = (const int*)d_in[2];
    float* out = (float*)d_out;

    const int D = in_sizes[1];                 // 128
    const int N = in_sizes[0] / D;             // 500000
    const int K = out_size / D;                // 2048
    (void)n_in; (void)ws_size;

    // workspace layout
    unsigned char* w = (unsigned char*)d_ws;
    float* y = (float*)w;                                       // N floats
    size_t off = ((size_t)N * sizeof(float) + 255) & ~(size_t)255;
    unsigned* hist = (unsigned*)(w + off);                      // HIST_BINS u32
    int* cnt = (int*)(w + off + HIST_BINS * sizeof(unsigned));  // 1 int (contiguous after hist)
    int* res = cnt + 1;                                         // 2 ints
    size_t off2 = (off + HIST_BINS * sizeof(unsigned) + 3 * sizeof(int) + 255) & ~(size_t)255;
    unsigned long long* pairs = (unsigned long long*)(w + off2); // SORTN u64

    hipMemsetAsync(hist, 0, HIST_BINS * sizeof(unsigned) + sizeof(int), stream);

    {   // scores: 2048 blocks x 256 threads = 8192 waves, contiguous chunks
        const int blocks = 2048;
        long long total_waves = (long long)blocks * 256 / 64;
        int rpw = (int)((N + total_waves - 1) / total_waves);
        rpw = (rpw + 1) & ~1;                  // even
        score_kernel<<<blocks, 256, 0, stream>>>(x, p, y, N, rpw);
    }
    hist_kernel<<<64, 1024, 0, stream>>>(y, hist, N);
    threshold_kernel<<<1, 1024, 0, stream>>>(hist, kptr, res);
    compact_kernel<<<(N + 255) / 256, 256, 0, stream>>>(y, res, pairs, cnt, N);
    sort_kernel<<<1, 1024, 0, stream>>>(pairs, cnt);
    gather_kernel<<<K, 128, 0, stream>>>(x, pairs, out);
}

// Round 3
// 422.901 us; speedup vs baseline: 4.9978x; 1.1962x over previous
//
#include <hip/hip_runtime.h>
#include <hip/hip_bf16.h>

// Problem: N=500000, D=128, K=2048
//  y = x @ p / ||p||; top_k(y, K) desc (ties -> lower index); out = x[idx] * tanh(vals)[:,None]

#define HIST_BITS 12
#define HIST_BINS (1 << HIST_BITS)   // 4096
#define HIST_SHIFT (32 - HIST_BITS)  // 20
#define SORTN 8192                   // candidate capacity (k + boundary bin, ~2800 expected)

__device__ __forceinline__ unsigned mono_key(float f) {
    unsigned u = __float_as_uint(f);
    return (u & 0x80000000u) ? ~u : (u | 0x80000000u);
}
__device__ __forceinline__ float mono_key_inv(unsigned mk) {
    unsigned u = (mk & 0x80000000u) ? (mk ^ 0x80000000u) : ~mk;
    return __uint_as_float(u);
}

// ---------------- kernel 1: scores only (NO atomics) ----------------
// 32 lanes per row, float4 loads: 2 rows per wave-iteration, 5 xor-shuffle rounds.
__global__ void score_kernel(const float* __restrict__ x, const float* __restrict__ p,
                             float* __restrict__ y, int N, int rpw) {
    int lane = threadIdx.x & 63;
    int half = lane >> 5;            // 0: even row of pair, 1: odd row
    int l32  = lane & 31;
    long long gwave = ((long long)blockIdx.x * blockDim.x + threadIdx.x) >> 6;
    long long start = gwave * rpw;
    if (start >= N) return;

    float4 pq = ((const float4*)p)[l32];
    double pp = (double)pq.x * pq.x + (double)pq.y * pq.y +
                (double)pq.z * pq.z + (double)pq.w * pq.w;
    #pragma unroll
    for (int off = 16; off > 0; off >>= 1) pp += __shfl_xor(pp, off, 64);
    double rinv = 1.0 / sqrt(pp);

    long long rend = start + rpw; if (rend > N) rend = N;
    for (long long r0 = start; r0 < rend; r0 += 2) {
        long long row = r0 + half;
        bool valid = row < N;
        float4 xq = valid ? ((const float4*)(x + row * 128))[l32]
                          : make_float4(0.f, 0.f, 0.f, 0.f);
        double d = (double)xq.x * pq.x + (double)xq.y * pq.y +
                   (double)xq.z * pq.z + (double)xq.w * pq.w;
        #pragma unroll
        for (int off = 16; off > 0; off >>= 1) d += __shfl_xor(d, off, 64);
        if (l32 == 0 && valid) y[row] = (float)(d * rinv);
    }
}

// ---------------- kernel 2: histogram over y (4 LDS sub-hists per block) ----------------
__global__ void hist_kernel(const float* __restrict__ y, unsigned* __restrict__ hist, int N) {
    __shared__ unsigned h[4][HIST_BINS];          // 64 KB
    for (int i = threadIdx.x; i < 4 * HIST_BINS; i += blockDim.x) h[0][i] = 0;
    __syncthreads();
    int sub = (threadIdx.x >> 6) & 3;             // wave id mod 4
    int stride = gridDim.x * blockDim.x;
    for (int i = blockIdx.x * blockDim.x + threadIdx.x; i < N; i += stride)
        atomicAdd(&h[sub][mono_key(y[i]) >> HIST_SHIFT], 1u);
    __syncthreads();
    for (int i = threadIdx.x; i < HIST_BINS; i += blockDim.x) {
        unsigned v = h[0][i] + h[1][i] + h[2][i] + h[3][i];
        if (v) atomicAdd(&hist[i], v);
    }
}

// ---------------- kernel 3: find threshold bin ----------------
__global__ void threshold_kernel(const unsigned* __restrict__ hist,
                                 const int* __restrict__ kptr, int* __restrict__ res) {
    __shared__ unsigned s[HIST_BINS];
    int t = threadIdx.x;             // 1024 threads
    for (int i = t; i < HIST_BINS; i += 1024) s[i] = hist[i];
    __syncthreads();
    for (int off = 1; off < HIST_BINS; off <<= 1) {
        unsigned v[HIST_BINS / 1024];
        #pragma unroll
        for (int j = 0; j < HIST_BINS / 1024; j++) {
            int i = t + j * 1024;
            v[j] = s[i] + ((i + off < HIST_BINS) ? s[i + off] : 0u);
        }
        __syncthreads();
        #pragma unroll
        for (int j = 0; j < HIST_BINS / 1024; j++) s[t + j * 1024] = v[j];
        __syncthreads();
    }
    int k = *kptr;
    #pragma unroll
    for (int j = 0; j < HIST_BINS / 1024; j++) {
        int i = t + j * 1024;
        int c     = (int)s[i];
        int cnext = (i + 1 < HIST_BINS) ? (int)s[i + 1] : 0;
        if (c >= k && cnext < k) { res[0] = i; res[1] = cnext; }
    }
}

// ---------------- kernel 4: compact candidates (block-aggregated atomic) ----------------
// key64 = mkey<<32 | ~idx  -> desc order == value desc, ties idx asc (jax tie-break)
__global__ void compact_kernel(const float* __restrict__ y, const int* __restrict__ res,
                               unsigned long long* __restrict__ pairs, int* __restrict__ cnt,
                               int N) {
    __shared__ int lcnt, lbase;
    if (threadIdx.x == 0) lcnt = 0;
    __syncthreads();
    int B = res[0];
    int i = blockIdx.x * blockDim.x + threadIdx.x;
    int lpos = -1;
    unsigned mk = 0;
    if (i < N) {
        mk = mono_key(y[i]);
        if ((int)(mk >> HIST_SHIFT) >= B) lpos = atomicAdd(&lcnt, 1);
    }
    __syncthreads();
    if (threadIdx.x == 0 && lcnt > 0) lbase = atomicAdd(cnt, lcnt);
    __syncthreads();
    if (lpos >= 0) {
        int pos = lbase + lpos;
        if (pos < SORTN)
            pairs[pos] = ((unsigned long long)mk << 32) | (unsigned)~(unsigned)i;
    }
}

// ---------------- kernel 5: rank-by-count selection (replaces bitonic sort) ----------------
// All keys unique (idx embedded) -> rank = #{keys > mine}; scatter into spairs[rank].
// Keys staged in LDS; inner loop reads are wave-uniform (broadcast, conflict-free).
__global__ void rank_kernel(const unsigned long long* __restrict__ pairs,
                            const int* __restrict__ cnt,
                            unsigned long long* __restrict__ spairs, int K) {
    __shared__ unsigned long long s[SORTN];       // 64 KB
    int n = *cnt; if (n > SORTN) n = SORTN;
    int npad = (n + 3) & ~3;                      // pad to multiple of 4 with 0-keys
    for (int i = threadIdx.x; i < npad; i += blockDim.x)
        s[i] = (i < n) ? pairs[i] : 0ull;         // 0 < any real key (scores>0 => top bit set)
    __syncthreads();
    int c = blockIdx.x * blockDim.x + threadIdx.x;
    if (c >= n) return;
    unsigned long long my = s[c];
    int r = 0;
    for (int i = 0; i < npad; i += 4) {
        unsigned long long a = s[i], b = s[i + 1], d = s[i + 2], e = s[i + 3];
        r += (a > my) + (b > my) + (d > my) + (e > my);
    }
    if (r < K) spairs[r] = my;
}

// ---------------- kernel 6: gather + tanh scale ----------------
__global__ void gather_kernel(const float* __restrict__ x,
                              const unsigned long long* __restrict__ spairs,
                              float* __restrict__ out) {
    int j = blockIdx.x;              // 0..K-1
    unsigned long long key = spairs[j];
    unsigned mk  = (unsigned)(key >> 32);
    unsigned idx = ~(unsigned)(key & 0xFFFFFFFFull);
    float scale = tanhf(mono_key_inv(mk));
    int t = threadIdx.x;             // 128 threads
    out[(size_t)j * 128 + t] = x[(size_t)idx * 128 + t] * scale;
}

extern "C" void kernel_launch(void* const* d_in, const int* in_sizes, int n_in,
                              void* d_out, int out_size, void* d_ws, size_t ws_size,
                              hipStream_t stream) {
    const float* x = (const float*)d_in[0];
    const float* p = (const float*)d_in[1];
    const int*   kptr = (const int*)d_in[2];
    float* out = (float*)d_out;

    const int D = in_sizes[1];                 // 128
    const int N = in_sizes[0] / D;             // 500000
    const int K = out_size / D;                // 2048
    (void)n_in; (void)ws_size;

    // workspace layout
    unsigned char* w = (unsigned char*)d_ws;
    float* y = (float*)w;                                       // N floats
    size_t off = ((size_t)N * sizeof(float) + 255) & ~(size_t)255;
    unsigned* hist = (unsigned*)(w + off);                      // HIST_BINS u32
    int* cnt = (int*)(w + off + HIST_BINS * sizeof(unsigned));  // 1 int (contiguous after hist)
    int* res = cnt + 1;                                         // 2 ints
    size_t off2 = (off + HIST_BINS * sizeof(unsigned) + 3 * sizeof(int) + 255) & ~(size_t)255;
    unsigned long long* pairs = (unsigned long long*)(w + off2); // SORTN u64
    unsigned long long* spairs = pairs + SORTN;                  // K u64 (sorted top-K)

    hipMemsetAsync(hist, 0, HIST_BINS * sizeof(unsigned) + sizeof(int), stream);

    {   // scores: 2048 blocks x 256 threads = 8192 waves, contiguous chunks
        const int blocks = 2048;
        long long total_waves = (long long)blocks * 256 / 64;
        int rpw = (int)((N + total_waves - 1) / total_waves);
        rpw = (rpw + 1) & ~1;                  // even
        score_kernel<<<blocks, 256, 0, stream>>>(x, p, y, N, rpw);
    }
    hist_kernel<<<64, 1024, 0, stream>>>(y, hist, N);
    threshold_kernel<<<1, 1024, 0, stream>>>(hist, kptr, res);
    compact_kernel<<<(N + 255) / 256, 256, 0, stream>>>(y, res, pairs, cnt, N);
    rank_kernel<<<SORTN / 256, 256, 0, stream>>>(pairs, cnt, spairs, K);
    gather_kernel<<<K, 128, 0, stream>>>(x, spairs, out);
}

// Round 4
// 397.043 us; speedup vs baseline: 5.3233x; 1.0651x over previous
//
#include <hip/hip_runtime.h>
#include <hip/hip_bf16.h>

// Problem: N=500000, D=128, K=2048
//  y = x @ p / ||p||; top_k(y, K) desc (ties -> lower index); out = x[idx] * tanh(vals)[:,None]

#define HIST_BITS 12
#define HIST_BINS (1 << HIST_BITS)   // 4096
#define HIST_SHIFT (32 - HIST_BITS)  // 20
#define SORTN 8192                   // candidate capacity (k + boundary bin, ~2800 expected)
#define SLICES 8                     // rank-count parallelism over the compare dimension

__device__ __forceinline__ unsigned mono_key(float f) {
    unsigned u = __float_as_uint(f);
    return (u & 0x80000000u) ? ~u : (u | 0x80000000u);
}
__device__ __forceinline__ float mono_key_inv(unsigned mk) {
    unsigned u = (mk & 0x80000000u) ? (mk ^ 0x80000000u) : ~mk;
    return __uint_as_float(u);
}

// ---------------- kernel 1: scores only (no atomics) ----------------
// 32 lanes per row, float4 loads; 4 rows per wave-iteration (2 independent chains).
__global__ void score_kernel(const float* __restrict__ x, const float* __restrict__ p,
                             float* __restrict__ y, int N, int rpw) {
    int lane = threadIdx.x & 63;
    int half = lane >> 5;            // 0: even row of pair, 1: odd row
    int l32  = lane & 31;
    long long gwave = ((long long)blockIdx.x * blockDim.x + threadIdx.x) >> 6;
    long long start = gwave * rpw;   // rpw even; N even -> row pairs always complete
    if (start >= N) return;

    float4 pq = ((const float4*)p)[l32];
    double pp = (double)pq.x * pq.x + (double)pq.y * pq.y +
                (double)pq.z * pq.z + (double)pq.w * pq.w;
    #pragma unroll
    for (int off = 16; off > 0; off >>= 1) pp += __shfl_xor(pp, off, 64);
    double rinv = 1.0 / sqrt(pp);

    long long rend = start + rpw; if (rend > N) rend = N;
    for (long long r0 = start; r0 < rend; r0 += 4) {
        long long rowA = r0 + half;
        long long rowB = r0 + 2 + half;
        bool vb = (r0 + 2) < rend;
        float4 xa = ((const float4*)(x + rowA * 128))[l32];
        float4 xb = vb ? ((const float4*)(x + rowB * 128))[l32]
                       : make_float4(0.f, 0.f, 0.f, 0.f);
        double dA = (double)xa.x * pq.x + (double)xa.y * pq.y +
                    (double)xa.z * pq.z + (double)xa.w * pq.w;
        double dB = (double)xb.x * pq.x + (double)xb.y * pq.y +
                    (double)xb.z * pq.z + (double)xb.w * pq.w;
        #pragma unroll
        for (int off = 16; off > 0; off >>= 1) {
            dA += __shfl_xor(dA, off, 64);
            dB += __shfl_xor(dB, off, 64);
        }
        if (l32 == 0) {
            y[rowA] = (float)(dA * rinv);
            if (vb) y[rowB] = (float)(dB * rinv);
        }
    }
}

// ---------------- kernel 2: histogram over y (4 LDS sub-hists per block) ----------------
__global__ void hist_kernel(const float* __restrict__ y, unsigned* __restrict__ hist, int N) {
    __shared__ unsigned h[4][HIST_BINS];          // 64 KB
    for (int i = threadIdx.x; i < 4 * HIST_BINS; i += blockDim.x) h[0][i] = 0;
    __syncthreads();
    int sub = (threadIdx.x >> 6) & 3;             // wave id mod 4
    int stride = gridDim.x * blockDim.x;
    for (int i = blockIdx.x * blockDim.x + threadIdx.x; i < N; i += stride)
        atomicAdd(&h[sub][mono_key(y[i]) >> HIST_SHIFT], 1u);
    __syncthreads();
    for (int i = threadIdx.x; i < HIST_BINS; i += blockDim.x) {
        unsigned v = h[0][i] + h[1][i] + h[2][i] + h[3][i];
        if (v) atomicAdd(&hist[i], v);
    }
}

// ---------------- kernel 3: find threshold bin ----------------
__global__ void threshold_kernel(const unsigned* __restrict__ hist,
                                 const int* __restrict__ kptr, int* __restrict__ res) {
    __shared__ unsigned s[HIST_BINS];
    int t = threadIdx.x;             // 1024 threads
    for (int i = t; i < HIST_BINS; i += 1024) s[i] = hist[i];
    __syncthreads();
    for (int off = 1; off < HIST_BINS; off <<= 1) {
        unsigned v[HIST_BINS / 1024];
        #pragma unroll
        for (int j = 0; j < HIST_BINS / 1024; j++) {
            int i = t + j * 1024;
            v[j] = s[i] + ((i + off < HIST_BINS) ? s[i + off] : 0u);
        }
        __syncthreads();
        #pragma unroll
        for (int j = 0; j < HIST_BINS / 1024; j++) s[t + j * 1024] = v[j];
        __syncthreads();
    }
    int k = *kptr;
    #pragma unroll
    for (int j = 0; j < HIST_BINS / 1024; j++) {
        int i = t + j * 1024;
        int c     = (int)s[i];
        int cnext = (i + 1 < HIST_BINS) ? (int)s[i + 1] : 0;
        if (c >= k && cnext < k) { res[0] = i; res[1] = cnext; }
    }
}

// ---------------- kernel 4: compact candidates (block-aggregated atomic) ----------------
// key64 = mkey<<32 | ~idx  -> desc order == value desc, ties idx asc (jax tie-break)
__global__ void compact_kernel(const float* __restrict__ y, const int* __restrict__ res,
                               unsigned long long* __restrict__ pairs, int* __restrict__ cnt,
                               int N) {
    __shared__ int lcnt, lbase;
    if (threadIdx.x == 0) lcnt = 0;
    __syncthreads();
    int B = res[0];
    int i = blockIdx.x * blockDim.x + threadIdx.x;
    int lpos = -1;
    unsigned mk = 0;
    if (i < N) {
        mk = mono_key(y[i]);
        if ((int)(mk >> HIST_SHIFT) >= B) lpos = atomicAdd(&lcnt, 1);
    }
    __syncthreads();
    if (threadIdx.x == 0 && lcnt > 0) lbase = atomicAdd(cnt, lcnt);
    __syncthreads();
    if (lpos >= 0) {
        int pos = lbase + lpos;
        if (pos < SORTN)
            pairs[pos] = ((unsigned long long)mk << 32) | (unsigned)~(unsigned)i;
    }
}

// ---------------- kernel 5a: rank partial counts (sliced compare dimension) ----------------
// grid (SORTN/256, SLICES); block (cb, sl) counts keys-in-slice-sl > candidate for 256 candidates.
__global__ void rank_count_kernel(const unsigned long long* __restrict__ pairs,
                                  const int* __restrict__ cnt,
                                  int* __restrict__ rankpart) {
    __shared__ unsigned long long s[SORTN / SLICES];   // 8 KB
    int n = *cnt; if (n > SORTN) n = SORTN;
    if ((int)(blockIdx.x * blockDim.x) >= n) return;   // whole block idle
    int npad = (n + 4 * SLICES - 1) & ~(4 * SLICES - 1);
    int slen = npad / SLICES;
    int sbeg = blockIdx.y * slen;
    for (int i = threadIdx.x; i < slen; i += blockDim.x) {
        int gi = sbeg + i;
        s[i] = (gi < n) ? pairs[gi] : 0ull;            // 0 < any real key (top bit set)
    }
    __syncthreads();
    int c = blockIdx.x * blockDim.x + threadIdx.x;
    if (c >= n) return;
    unsigned long long my = pairs[c];
    int r = 0;
    for (int i = 0; i < slen; i += 4)
        r += (int)(s[i] > my) + (int)(s[i+1] > my) + (int)(s[i+2] > my) + (int)(s[i+3] > my);
    rankpart[blockIdx.y * SORTN + c] = r;
}

// ---------------- kernel 5b: sum partials + scatter into sorted order ----------------
__global__ void rank_scatter_kernel(const unsigned long long* __restrict__ pairs,
                                    const int* __restrict__ cnt,
                                    const int* __restrict__ rankpart,
                                    unsigned long long* __restrict__ spairs, int K) {
    int n = *cnt; if (n > SORTN) n = SORTN;
    int c = blockIdx.x * blockDim.x + threadIdx.x;
    if (c >= n) return;
    int r = 0;
    #pragma unroll
    for (int sl = 0; sl < SLICES; sl++) r += rankpart[sl * SORTN + c];
    if (r < K) spairs[r] = pairs[c];
}

// ---------------- kernel 6: gather + tanh scale ----------------
__global__ void gather_kernel(const float* __restrict__ x,
                              const unsigned long long* __restrict__ spairs,
                              float* __restrict__ out) {
    int j = blockIdx.x;              // 0..K-1
    unsigned long long key = spairs[j];
    unsigned mk  = (unsigned)(key >> 32);
    unsigned idx = ~(unsigned)(key & 0xFFFFFFFFull);
    float scale = tanhf(mono_key_inv(mk));
    int t = threadIdx.x;             // 128 threads
    out[(size_t)j * 128 + t] = x[(size_t)idx * 128 + t] * scale;
}

extern "C" void kernel_launch(void* const* d_in, const int* in_sizes, int n_in,
                              void* d_out, int out_size, void* d_ws, size_t ws_size,
                              hipStream_t stream) {
    const float* x = (const float*)d_in[0];
    const float* p = (const float*)d_in[1];
    const int*   kptr = (const int*)d_in[2];
    float* out = (float*)d_out;

    const int D = in_sizes[1];                 // 128
    const int N = in_sizes[0] / D;             // 500000
    const int K = out_size / D;                // 2048
    (void)n_in; (void)ws_size;

    // workspace layout
    unsigned char* w = (unsigned char*)d_ws;
    float* y = (float*)w;                                       // N floats
    size_t off = ((size_t)N * sizeof(float) + 255) & ~(size_t)255;
    unsigned* hist = (unsigned*)(w + off);                      // HIST_BINS u32
    int* cnt = (int*)(w + off + HIST_BINS * sizeof(unsigned));  // 1 int (contiguous after hist)
    int* res = cnt + 1;                                         // 2 ints
    size_t off2 = (off + HIST_BINS * sizeof(unsigned) + 3 * sizeof(int) + 255) & ~(size_t)255;
    unsigned long long* pairs = (unsigned long long*)(w + off2); // SORTN u64
    unsigned long long* spairs = pairs + SORTN;                  // K u64 (sorted top-K)
    int* rankpart = (int*)(spairs + SORTN);                      // SLICES*SORTN ints

    hipMemsetAsync(hist, 0, HIST_BINS * sizeof(unsigned) + sizeof(int), stream);

    {   // scores: 2048 blocks x 256 threads = 8192 waves, contiguous chunks
        const int blocks = 2048;
        long long total_waves = (long long)blocks * 256 / 64;
        int rpw = (int)((N + total_waves - 1) / total_waves);
        rpw = (rpw + 1) & ~1;                  // even
        score_kernel<<<blocks, 256, 0, stream>>>(x, p, y, N, rpw);
    }
    hist_kernel<<<64, 1024, 0, stream>>>(y, hist, N);
    threshold_kernel<<<1, 1024, 0, stream>>>(hist, kptr, res);
    compact_kernel<<<(N + 255) / 256, 256, 0, stream>>>(y, res, pairs, cnt, N);
    rank_count_kernel<<<dim3(SORTN / 256, SLICES), 256, 0, stream>>>(pairs, cnt, rankpart);
    rank_scatter_kernel<<<SORTN / 256, 256, 0, stream>>>(pairs, cnt, rankpart, spairs, K);
    gather_kernel<<<K, 128, 0, stream>>>(x, spairs, out);
}